// Round 18
// baseline (765.879 us; speedup 1.0000x reference)
//
#include <hip/hip_runtime.h>
#include <math.h>

#define DIM   256
#define NP    512
#define RB    16
#define NT    256
#define PITCH 260            // xs row pitch in floats (1040 B: 16B-aligned, bank spread)
#define CAND_CAP 16
#define KSEL  5

typedef float f32x4 __attribute__((ext_vector_type(4)));
typedef short short8 __attribute__((ext_vector_type(8)));

__device__ __forceinline__ unsigned short f32_to_bf16_rne(float f) {
    unsigned u = __float_as_uint(f);
    u += 0x7FFFu + ((u >> 16) & 1u);
    return (unsigned short)(u >> 16);
}

// One-shot: protos f32 [512][256] -> bf16 (truncation, bit-identical to rounds 5-17 B path)
// in MFMA-fragment order: pbf[(((pg*8+ks)*4+kq)*16+m)*8+dd] = trunc(protos[pg*16+m][ks*32+kq*8+dd])
__global__ __launch_bounds__(256) void protos_pack(const float* __restrict__ protos,
                                                   unsigned short* __restrict__ pbf) {
    int t  = blockIdx.x * 256 + threadIdx.x;       // 131072 threads
    int dd = t & 7;
    int m  = (t >> 3) & 15;
    int kq = (t >> 7) & 3;
    int ks = (t >> 9) & 7;
    int pg = t >> 12;
    float v = protos[(pg * 16 + m) * DIM + ks * 32 + kq * 8 + dd];
    pbf[t] = (unsigned short)(__float_as_uint(v) >> 16);
}

__global__ __launch_bounds__(NT, 8) void hub_kernel(
    const float* __restrict__ x,
    const float* __restrict__ protos,
    const unsigned short* __restrict__ pbf,        // fragment-ordered bf16 protos (d_ws)
    float* __restrict__ out)
{
    __shared__ float          xs[RB * PITCH];      // 16640 B (raw x, then xn)
    __shared__ unsigned       selbuf[RB * 4 * KSEL]; // 1280 B: ktop, later overlaid by cval
    __shared__ unsigned       u5[RB];              // exact union 5th-largest key
    __shared__ int            scnt[RB];
    __shared__ unsigned short cidx[RB][CAND_CAP];
    __shared__ float          top5v[RB][KSEL];
    __shared__ int            top5i[RB][KSEL];

    unsigned (*ktop)[4][KSEL] = (unsigned(*)[4][KSEL])selbuf;   // live: selection..u5
    float    (*cval)[CAND_CAP] = (float(*)[CAND_CAP])selbuf;    // live: refine..top5 (disjoint)

    const int tid  = threadIdx.x;
    const int wave = tid >> 6;
    const int lane = tid & 63;

    // ---- XCD-chunked bijective swizzle (R14: FETCH -40%, WRITE -28%) ----
    const int bid  = blockIdx.x;
    const int cpx  = gridDim.x >> 3;               // 2048 blocks per XCD chunk
    const int wid  = (bid & 7) * cpx + (bid >> 3);
    const size_t r0 = (size_t)wid * RB;
    float* outb = out + r0 * NP;

    // ---- stage x tile (coalesced float4) into padded LDS ----
    {
        const float4* xg = (const float4*)(x + r0 * DIM);
        #pragma unroll
        for (int i = 0; i < 4; ++i) {              // 1024 float4 / 256 thr
            int fi = tid + i * NT;
            int r = fi >> 6, c4 = fi & 63;
            *(float4*)(&xs[r * PITCH + c4 * 4]) = xg[fi];
        }
        if (tid < RB) scnt[tid] = 0;
    }
    __syncthreads();

    // ---- fused norm+normalize: wave w owns rows 4w..4w+3; f64 butterfly leaves
    //      the full sum in EVERY lane (frozen numerics) ----
    #pragma unroll
    for (int rr = 0; rr < 4; ++rr) {
        int r = wave * 4 + rr;
        double sq = 0.0;
        #pragma unroll
        for (int j = 0; j < 4; ++j) { double xv = (double)xs[r * PITCH + lane * 4 + j]; sq += xv * xv; }
        #pragma unroll
        for (int s = 32; s > 0; s >>= 1) sq += __shfl_xor(sq, s);
        float nr = fmaxf(sqrtf((float)sq), 1e-12f);
        #pragma unroll
        for (int j = 0; j < 4; ++j)
            xs[r * PITCH + lane * 4 + j] = xs[r * PITCH + lane * 4 + j] / nr;
    }
    __syncthreads();

    // ---- per-wave geometry: all waves share the 16 rows; wave owns proto quarter ----
    const int qg     = wave;                       // proto quarter: qg*128 .. +128
    const int mylane = lane & 15;
    const int kq     = lane >> 4;                  // k-octet within 32-chunk
    const int g      = lane >> 4;                  // C-layout row group

    // ---- screening MFMA: 16 rows x 128 protos per wave; B from global (L2);
    //      double-buffered B prefetch hides L2 latency under MFMA+A-convert ----
    const short8* __restrict__ pbf8 = (const short8*)pbf + (size_t)qg * 4096 + lane;
    f32x4 acc[8];
    #pragma unroll
    for (int t2 = 0; t2 < 8; ++t2) acc[t2] = (f32x4)(0.0f);

    short8 bb[2][8];
    #pragma unroll
    for (int t2 = 0; t2 < 8; ++t2) bb[0][t2] = pbf8[t2 * 512];   // ks=0 prologue

    #pragma unroll
    for (int ks = 0; ks < 8; ++ks) {
        if (ks < 7) {
            #pragma unroll
            for (int t2 = 0; t2 < 8; ++t2)
                bb[(ks + 1) & 1][t2] = pbf8[t2 * 512 + (ks + 1) * 64];
        }
        const float* src = &xs[mylane * PITCH + ks * 32 + kq * 8];
        float4 f0 = *(const float4*)(src);
        float4 f1 = *(const float4*)(src + 4);
        short8 a;
        a[0] = (short)f32_to_bf16_rne(f0.x); a[1] = (short)f32_to_bf16_rne(f0.y);
        a[2] = (short)f32_to_bf16_rne(f0.z); a[3] = (short)f32_to_bf16_rne(f0.w);
        a[4] = (short)f32_to_bf16_rne(f1.x); a[5] = (short)f32_to_bf16_rne(f1.y);
        a[6] = (short)f32_to_bf16_rne(f1.z); a[7] = (short)f32_to_bf16_rne(f1.w);
        #pragma unroll
        for (int t2 = 0; t2 < 8; ++t2)
            acc[t2] = __builtin_amdgcn_mfma_f32_16x16x32_bf16(a, bb[ks & 1][t2], acc[t2], 0, 0, 0);
    }

    // ---- per-quarter top-5 keys per row (descending), packed u32: monotone val | idx ----
    // C layout: col = lane&15 (proto), row = (lane>>4)*4 + reg  [m89-verified]
    #pragma unroll
    for (int m = 0; m < 4; ++m) {
        unsigned keys[8];
        #pragma unroll
        for (int t2 = 0; t2 < 8; ++t2) {
            unsigned u = __float_as_uint(fmaf(acc[t2][m], 0.25f, 1.5f));   // [1.25,1.75): fixed exp, monotone
            keys[t2] = (u & 0xFFFFFE00u) | (unsigned)(qg * 128 + t2 * 16 + mylane);
        }
        #pragma unroll
        for (int it = 0; it < KSEL; ++it) {
            unsigned loc = 0;
            #pragma unroll
            for (int t2 = 0; t2 < 8; ++t2) loc = keys[t2] > loc ? keys[t2] : loc;
            #pragma unroll
            for (int s = 1; s < 16; s <<= 1) {                 // 16-lane group reduce
                unsigned o = (unsigned)__shfl_xor((int)loc, s);
                loc = o > loc ? o : loc;
            }
            if (mylane == 0) ktop[g * 4 + m][qg][it] = loc;
            if (it < KSEL - 1) {                               // last elimination is dead
                #pragma unroll
                for (int t2 = 0; t2 < 8; ++t2) keys[t2] = (keys[t2] == loc) ? 0u : keys[t2];
            }
        }
    }
    __syncthreads();

    // ---- EXACT union 5th-largest key: merge 4 descending 5-lists pairwise ----
    if (tid < RB) {
        unsigned A[KSEL], B[KSEL], M1[KSEL], M2[KSEL];
        #pragma unroll
        for (int j = 0; j < KSEL; ++j) { A[j] = ktop[tid][0][j]; B[j] = ktop[tid][1][j]; }
        { int i = 0, j = 0;
          #pragma unroll
          for (int s = 0; s < KSEL; ++s) { M1[s] = (A[i] >= B[j]) ? A[i++] : B[j++]; } }
        #pragma unroll
        for (int j = 0; j < KSEL; ++j) { A[j] = ktop[tid][2][j]; B[j] = ktop[tid][3][j]; }
        { int i = 0, j = 0;
          #pragma unroll
          for (int s = 0; s < KSEL; ++s) { M2[s] = (A[i] >= B[j]) ? A[i++] : B[j++]; } }
        { int i = 0, j = 0; unsigned last = 0;
          #pragma unroll
          for (int s = 0; s < KSEL; ++s) { last = (M1[i] >= M2[j]) ? M1[i++] : M2[j++]; }
          u5[tid] = last; }
    }
    __syncthreads();

    // ---- candidate collection: key >= union5th - margin(1.95e-3) ----
    #pragma unroll
    for (int m = 0; m < 4; ++m) {
        int row = g * 4 + m;
        unsigned tk = (u5[row] & 0xFFFFFE00u) - 0x1000u;
        #pragma unroll
        for (int t2 = 0; t2 < 8; ++t2) {
            unsigned u = __float_as_uint(fmaf(acc[t2][m], 0.25f, 1.5f)) & 0xFFFFFE00u;
            if (u >= tk) {
                int slot = atomicAdd(&scnt[row], 1);
                if (slot < CAND_CAP) cidx[row][slot] = (unsigned short)(qg * 128 + t2 * 16 + mylane);
            }
        }
    }
    __syncthreads();

    // ---- exact refine: frozen d-ascending fmaf chain; 16 threads/row, 1 proto each ----
    {
        int row = tid >> 4;
        int slot = tid & 15;
        int n = min(scnt[row], CAND_CAP);
        if (slot < n) {
            int p = (int)cidx[row][slot];
            const float4* pr = (const float4*)(protos + (size_t)p * DIM);
            const float* xr = &xs[row * PITCH];
            float a0 = 0.f;
            #pragma unroll 8
            for (int d4 = 0; d4 < 64; ++d4) {
                float4 xv = *(const float4*)(xr + d4 * 4);
                float4 q = pr[d4];
                a0 = fmaf(xv.x, q.x, a0); a0 = fmaf(xv.y, q.y, a0);
                a0 = fmaf(xv.z, q.z, a0); a0 = fmaf(xv.w, q.w, a0);
            }
            cval[row][slot] = a0;
        }
    }
    __syncthreads();

    // ---- exact top-5 among candidates (low-index ties) + f32 softmax ----
    if (tid < RB) {
        int row = tid;
        int n = min(scnt[row], CAND_CAP);
        float vv[CAND_CAP]; int ii[CAND_CAP];
        #pragma unroll
        for (int j = 0; j < CAND_CAP; ++j) {
            vv[j] = (j < n) ? cval[row][j] : -1e30f;
            ii[j] = (j < n) ? (int)cidx[row][j] : 0x7fffffff;
        }
        float vsel[KSEL]; int isel[KSEL];
        #pragma unroll
        for (int it = 0; it < KSEL; ++it) {
            float bv = -1e30f; int bi = 0x7fffffff;
            #pragma unroll
            for (int j = 0; j < CAND_CAP; ++j)
                if (vv[j] > bv || (vv[j] == bv && ii[j] < bi)) { bv = vv[j]; bi = ii[j]; }
            vsel[it] = bv; isel[it] = bi;
            #pragma unroll
            for (int j = 0; j < CAND_CAP; ++j)
                if (ii[j] == bi) { vv[j] = -1e30f; ii[j] = 0x7fffffff; }
        }
        float z[KSEL];
        #pragma unroll
        for (int it = 0; it < KSEL; ++it) z[it] = vsel[it] / 0.2f;
        float mm = z[0]; float e[KSEL]; float sum = 0.0f;
        #pragma unroll
        for (int it = 0; it < KSEL; ++it) { e[it] = expf(z[it] - mm); sum += e[it]; }
        #pragma unroll
        for (int it = 0; it < KSEL; ++it) {
            top5v[row][it] = e[it] / sum;
            top5i[row][it] = isel[it];
        }
    }
    __syncthreads();

    // ---- FUSED single-pass writeout: every output line written exactly once
    //      with values embedded (compare-select) -> no zeros, no scatter, no
    //      RMW window, no output reads. Occ-8-safe by construction. ----
    #pragma unroll
    for (int i = 0; i < 8; ++i) {
        int fi = tid + i * NT;
        int r = fi >> 7, c0 = (fi & 127) << 2;
        float4 vv = make_float4(0.f, 0.f, 0.f, 0.f);
        #pragma unroll
        for (int j = 0; j < KSEL; ++j) {
            int   idx = top5i[r][j];
            float val = top5v[r][j];
            if (c0     == idx) vv.x = val;
            if (c0 + 1 == idx) vv.y = val;
            if (c0 + 2 == idx) vv.z = val;
            if (c0 + 3 == idx) vv.w = val;
        }
        ((float4*)outb)[fi] = vv;
    }
}

extern "C" void kernel_launch(void* const* d_in, const int* in_sizes, int n_in,
                              void* d_out, int out_size, void* d_ws, size_t ws_size,
                              hipStream_t stream) {
    const float* x      = (const float*)d_in[0];
    const float* protos = (const float*)d_in[1];
    float* out = (float*)d_out;
    unsigned short* pbf = (unsigned short*)d_ws;   // 256 KB (proven available since R5)
    const int rows   = in_sizes[0] / DIM;          // 262144
    const int blocks = rows / RB;                  // 16384

    hipLaunchKernelGGL(protos_pack, dim3(512), dim3(256), 0, stream, protos, pbf);
    hipLaunchKernelGGL(hub_kernel, dim3(blocks), dim3(NT), 0, stream,
                       x, protos, pbf, out);
}

// Round 19
// 517.757 us; speedup vs baseline: 1.4792x; 1.4792x over previous
//
#include <hip/hip_runtime.h>
#include <math.h>

#define DIM   256
#define NP    512
#define RB    16
#define NT    256
#define PITCH 260            // xs row pitch in floats (1040 B: 16B-aligned, bank spread)
#define CAND_CAP 16
#define KSEL  5

typedef float f32x4 __attribute__((ext_vector_type(4)));
typedef short short8 __attribute__((ext_vector_type(8)));

__device__ __forceinline__ unsigned short f32_to_bf16_rne(float f) {
    unsigned u = __float_as_uint(f);
    u += 0x7FFFu + ((u >> 16) & 1u);
    return (unsigned short)(u >> 16);
}

// One-shot: protos f32 [512][256] -> bf16 (truncation, bit-identical to rounds 5-18 B path)
// in MFMA-fragment order: pbf[(((pg*8+ks)*4+kq)*16+m)*8+dd] = trunc(protos[pg*16+m][ks*32+kq*8+dd])
__global__ __launch_bounds__(256) void protos_pack(const float* __restrict__ protos,
                                                   unsigned short* __restrict__ pbf) {
    int t  = blockIdx.x * 256 + threadIdx.x;       // 131072 threads
    int dd = t & 7;
    int m  = (t >> 3) & 15;
    int kq = (t >> 7) & 3;
    int ks = (t >> 9) & 7;
    int pg = t >> 12;
    float v = protos[(pg * 16 + m) * DIM + ks * 32 + kq * 8 + dd];
    pbf[t] = (unsigned short)(__float_as_uint(v) >> 16);
}

__global__ __launch_bounds__(NT, 6) void hub_kernel(
    const float* __restrict__ x,
    const float* __restrict__ protos,
    const unsigned short* __restrict__ pbf,        // fragment-ordered bf16 protos (d_ws)
    float* __restrict__ out)
{
    __shared__ float          xs[RB * PITCH];      // 16640 B (raw x, then xn)
    __shared__ unsigned       selbuf[RB * 4 * KSEL]; // 1280 B: ktop, later overlaid by cval
    __shared__ unsigned       u5[RB];              // exact union 5th-largest key
    __shared__ int            scnt[RB];
    __shared__ unsigned short cidx[RB][CAND_CAP];
    __shared__ float          top5v[RB][KSEL];
    __shared__ int            top5i[RB][KSEL];

    unsigned (*ktop)[4][KSEL] = (unsigned(*)[4][KSEL])selbuf;   // live: selection..u5
    float    (*cval)[CAND_CAP] = (float(*)[CAND_CAP])selbuf;    // live: refine..top5 (disjoint)

    const int tid  = threadIdx.x;
    const int wave = tid >> 6;
    const int lane = tid & 63;

    // ---- XCD-chunked bijective swizzle (R14: FETCH -40%, WRITE -28%) ----
    const int bid  = blockIdx.x;
    const int cpx  = gridDim.x >> 3;               // 2048 blocks per XCD chunk
    const int wid  = (bid & 7) * cpx + (bid >> 3);
    const size_t r0 = (size_t)wid * RB;
    float* outb = out + r0 * NP;

    // ---- stage x tile (coalesced float4) into padded LDS ----
    {
        const float4* xg = (const float4*)(x + r0 * DIM);
        #pragma unroll
        for (int i = 0; i < 4; ++i) {              // 1024 float4 / 256 thr
            int fi = tid + i * NT;
            int r = fi >> 6, c4 = fi & 63;
            *(float4*)(&xs[r * PITCH + c4 * 4]) = xg[fi];
        }
        if (tid < RB) scnt[tid] = 0;
    }
    __syncthreads();

    // ---- fused norm+normalize: wave w owns rows 4w..4w+3; f64 butterfly leaves
    //      the full sum in EVERY lane (frozen numerics) ----
    #pragma unroll
    for (int rr = 0; rr < 4; ++rr) {
        int r = wave * 4 + rr;
        double sq = 0.0;
        #pragma unroll
        for (int j = 0; j < 4; ++j) { double xv = (double)xs[r * PITCH + lane * 4 + j]; sq += xv * xv; }
        #pragma unroll
        for (int s = 32; s > 0; s >>= 1) sq += __shfl_xor(sq, s);
        float nr = fmaxf(sqrtf((float)sq), 1e-12f);
        #pragma unroll
        for (int j = 0; j < 4; ++j)
            xs[r * PITCH + lane * 4 + j] = xs[r * PITCH + lane * 4 + j] / nr;
    }
    __syncthreads();

    // ---- per-wave geometry: all waves share the 16 rows; wave owns proto quarter ----
    const int qg     = wave;                       // proto quarter: qg*128 .. +128
    const int mylane = lane & 15;
    const int kq     = lane >> 4;                  // k-octet within 32-chunk
    const int g      = lane >> 4;                  // C-layout row group

    // ---- screening MFMA: 16 rows x 128 protos per wave; B from global (L2);
    //      double-buffered B prefetch hides L2 latency under MFMA+A-convert ----
    const short8* __restrict__ pbf8 = (const short8*)pbf + (size_t)qg * 4096 + lane;
    f32x4 acc[8];
    #pragma unroll
    for (int t2 = 0; t2 < 8; ++t2) acc[t2] = (f32x4)(0.0f);

    short8 bb[2][8];
    #pragma unroll
    for (int t2 = 0; t2 < 8; ++t2) bb[0][t2] = pbf8[t2 * 512];   // ks=0 prologue

    #pragma unroll
    for (int ks = 0; ks < 8; ++ks) {
        if (ks < 7) {
            #pragma unroll
            for (int t2 = 0; t2 < 8; ++t2)
                bb[(ks + 1) & 1][t2] = pbf8[t2 * 512 + (ks + 1) * 64];
        }
        const float* src = &xs[mylane * PITCH + ks * 32 + kq * 8];
        float4 f0 = *(const float4*)(src);
        float4 f1 = *(const float4*)(src + 4);
        short8 a;
        a[0] = (short)f32_to_bf16_rne(f0.x); a[1] = (short)f32_to_bf16_rne(f0.y);
        a[2] = (short)f32_to_bf16_rne(f0.z); a[3] = (short)f32_to_bf16_rne(f0.w);
        a[4] = (short)f32_to_bf16_rne(f1.x); a[5] = (short)f32_to_bf16_rne(f1.y);
        a[6] = (short)f32_to_bf16_rne(f1.z); a[7] = (short)f32_to_bf16_rne(f1.w);
        #pragma unroll
        for (int t2 = 0; t2 < 8; ++t2)
            acc[t2] = __builtin_amdgcn_mfma_f32_16x16x32_bf16(a, bb[ks & 1][t2], acc[t2], 0, 0, 0);
    }

    // ---- per-quarter top-5 keys per row (descending), packed u32: monotone val | idx ----
    // C layout: col = lane&15 (proto), row = (lane>>4)*4 + reg  [m89-verified]
    #pragma unroll
    for (int m = 0; m < 4; ++m) {
        unsigned keys[8];
        #pragma unroll
        for (int t2 = 0; t2 < 8; ++t2) {
            unsigned u = __float_as_uint(fmaf(acc[t2][m], 0.25f, 1.5f));   // [1.25,1.75): fixed exp, monotone
            keys[t2] = (u & 0xFFFFFE00u) | (unsigned)(qg * 128 + t2 * 16 + mylane);
        }
        #pragma unroll
        for (int it = 0; it < KSEL; ++it) {
            unsigned loc = 0;
            #pragma unroll
            for (int t2 = 0; t2 < 8; ++t2) loc = keys[t2] > loc ? keys[t2] : loc;
            #pragma unroll
            for (int s = 1; s < 16; s <<= 1) {                 // 16-lane group reduce
                unsigned o = (unsigned)__shfl_xor((int)loc, s);
                loc = o > loc ? o : loc;
            }
            if (mylane == 0) ktop[g * 4 + m][qg][it] = loc;
            if (it < KSEL - 1) {                               // last elimination is dead
                #pragma unroll
                for (int t2 = 0; t2 < 8; ++t2) keys[t2] = (keys[t2] == loc) ? 0u : keys[t2];
            }
        }
    }
    __syncthreads();

    // ---- EXACT union 5th-largest key: merge 4 descending 5-lists pairwise ----
    if (tid < RB) {
        unsigned A[KSEL], B[KSEL], M1[KSEL], M2[KSEL];
        #pragma unroll
        for (int j = 0; j < KSEL; ++j) { A[j] = ktop[tid][0][j]; B[j] = ktop[tid][1][j]; }
        { int i = 0, j = 0;
          #pragma unroll
          for (int s = 0; s < KSEL; ++s) { M1[s] = (A[i] >= B[j]) ? A[i++] : B[j++]; } }
        #pragma unroll
        for (int j = 0; j < KSEL; ++j) { A[j] = ktop[tid][2][j]; B[j] = ktop[tid][3][j]; }
        { int i = 0, j = 0;
          #pragma unroll
          for (int s = 0; s < KSEL; ++s) { M2[s] = (A[i] >= B[j]) ? A[i++] : B[j++]; } }
        { int i = 0, j = 0; unsigned last = 0;
          #pragma unroll
          for (int s = 0; s < KSEL; ++s) { last = (M1[i] >= M2[j]) ? M1[i++] : M2[j++]; }
          u5[tid] = last; }
    }
    __syncthreads();

    // ---- candidate collection: key >= union5th - margin(1.95e-3) ----
    #pragma unroll
    for (int m = 0; m < 4; ++m) {
        int row = g * 4 + m;
        unsigned tk = (u5[row] & 0xFFFFFE00u) - 0x1000u;
        #pragma unroll
        for (int t2 = 0; t2 < 8; ++t2) {
            unsigned u = __float_as_uint(fmaf(acc[t2][m], 0.25f, 1.5f)) & 0xFFFFFE00u;
            if (u >= tk) {
                int slot = atomicAdd(&scnt[row], 1);
                if (slot < CAND_CAP) cidx[row][slot] = (unsigned short)(qg * 128 + t2 * 16 + mylane);
            }
        }
    }
    __syncthreads();

    // ---- exact refine: frozen d-ascending fmaf chain; 16 threads/row, 1 proto each ----
    {
        int row = tid >> 4;
        int slot = tid & 15;
        int n = min(scnt[row], CAND_CAP);
        if (slot < n) {
            int p = (int)cidx[row][slot];
            const float4* pr = (const float4*)(protos + (size_t)p * DIM);
            const float* xr = &xs[row * PITCH];
            float a0 = 0.f;
            #pragma unroll 8
            for (int d4 = 0; d4 < 64; ++d4) {
                float4 xv = *(const float4*)(xr + d4 * 4);
                float4 q = pr[d4];
                a0 = fmaf(xv.x, q.x, a0); a0 = fmaf(xv.y, q.y, a0);
                a0 = fmaf(xv.z, q.z, a0); a0 = fmaf(xv.w, q.w, a0);
            }
            cval[row][slot] = a0;
        }
    }
    __syncthreads();

    // ---- exact top-5 among candidates (low-index ties) + f32 softmax ----
    if (tid < RB) {
        int row = tid;
        int n = min(scnt[row], CAND_CAP);
        float vv[CAND_CAP]; int ii[CAND_CAP];
        #pragma unroll
        for (int j = 0; j < CAND_CAP; ++j) {
            vv[j] = (j < n) ? cval[row][j] : -1e30f;
            ii[j] = (j < n) ? (int)cidx[row][j] : 0x7fffffff;
        }
        float vsel[KSEL]; int isel[KSEL];
        #pragma unroll
        for (int it = 0; it < KSEL; ++it) {
            float bv = -1e30f; int bi = 0x7fffffff;
            #pragma unroll
            for (int j = 0; j < CAND_CAP; ++j)
                if (vv[j] > bv || (vv[j] == bv && ii[j] < bi)) { bv = vv[j]; bi = ii[j]; }
            vsel[it] = bv; isel[it] = bi;
            #pragma unroll
            for (int j = 0; j < CAND_CAP; ++j)
                if (ii[j] == bi) { vv[j] = -1e30f; ii[j] = 0x7fffffff; }
        }
        float z[KSEL];
        #pragma unroll
        for (int it = 0; it < KSEL; ++it) z[it] = vsel[it] / 0.2f;
        float mm = z[0]; float e[KSEL]; float sum = 0.0f;
        #pragma unroll
        for (int it = 0; it < KSEL; ++it) { e[it] = expf(z[it] - mm); sum += e[it]; }
        #pragma unroll
        for (int it = 0; it < KSEL; ++it) {
            top5v[row][it] = e[it] / sum;
            top5i[row][it] = isel[it];
        }
    }
    __syncthreads();

    // ---- writeout: stream zeros, barrier (drains vmcnt), scatter 5 dwords/row
    //      (minimal zero->scatter window: the R14-verified no-thrash regime) ----
    {
        const float4 zz = make_float4(0.f, 0.f, 0.f, 0.f);
        #pragma unroll
        for (int i = 0; i < 8; ++i)
            ((float4*)outb)[tid + i * NT] = zz;
    }
    __syncthreads();
    if (tid < RB * KSEL) {                         // 80 threads
        int row = tid / KSEL, j = tid - row * KSEL;
        outb[row * NP + top5i[row][j]] = top5v[row][j];
    }
}

extern "C" void kernel_launch(void* const* d_in, const int* in_sizes, int n_in,
                              void* d_out, int out_size, void* d_ws, size_t ws_size,
                              hipStream_t stream) {
    const float* x      = (const float*)d_in[0];
    const float* protos = (const float*)d_in[1];
    float* out = (float*)d_out;
    unsigned short* pbf = (unsigned short*)d_ws;   // 256 KB (proven available since R5)
    const int rows   = in_sizes[0] / DIM;          // 262144
    const int blocks = rows / RB;                  // 16384

    hipLaunchKernelGGL(protos_pack, dim3(512), dim3(256), 0, stream, protos, pbf);
    hipLaunchKernelGGL(hub_kernel, dim3(blocks), dim3(NT), 0, stream,
                       x, protos, pbf, out);
}